// Round 2
// baseline (434.870 us; speedup 1.0000x reference)
//
#include <hip/hip_runtime.h>
#include <math.h>

#define KDIM 64
#define TDIM 100
#define VDIM 10000
#define NV4  2500            // VDIM / 4
#define BLOCK 512
#define NWAVE (BLOCK / 64)
#define VPT 5                // ceil(NV4 / BLOCK)
#define CHUNK 5
#define NCHUNK (TDIM / CHUNK)

__device__ __forceinline__ float wave_red_sum(float v) {
#pragma unroll
    for (int m = 32; m >= 1; m >>= 1) v += __shfl_xor(v, m, 64);
    return v;
}
__device__ __forceinline__ float wave_red_max(float v) {
#pragma unroll
    for (int m = 32; m >= 1; m >>= 1) v = fmaxf(v, __shfl_xor(v, m, 64));
    return v;
}

__global__ __launch_bounds__(BLOCK, 8) void fused_beta_softmax_kl(
    const float* __restrict__ mu_q,   // [K, T, V]
    const float* __restrict__ lsq,    // [K, T, V]
    const float* __restrict__ eps,    // [T, K, V]
    float* __restrict__ out,          // [T, K, V]
    float* __restrict__ kl)           // scalar (pre-zeroed)
{
    __shared__ float red[NWAVE];

    const int tid = threadIdx.x;
    const int bid = blockIdx.x;
    const int k   = bid / NCHUNK;
    const int c   = bid % NCHUNK;
    const int t0  = c * CHUNK;

    const float inv1 = 1.0f / (1.0f + 1e-6f);
    const float invd = 1.0f / (0.005f + 1e-6f);
    const float logd = -5.2983173665480363f;   // log(0.005f) in fp32

    float4 bprev[VPT];
    float  klacc = 0.0f;

    // ---- chunk-boundary: recompute beta[t0-1] into registers ----
    if (t0 > 0) {
        const size_t po = ((size_t)k * TDIM + (t0 - 1)) * VDIM;
        const size_t eo = ((size_t)(t0 - 1) * KDIM + k) * VDIM;
        const float4* m4p = reinterpret_cast<const float4*>(mu_q + po);
        const float4* l4p = reinterpret_cast<const float4*>(lsq + po);
        const float4* e4p = reinterpret_cast<const float4*>(eps + eo);
#pragma unroll
        for (int j = 0; j < VPT; ++j) {
            const int idx = tid + j * BLOCK;
            if (idx < NV4) {
                const float4 m = m4p[idx];
                const float4 l = l4p[idx];
                const float4 e = e4p[idx];
                float4 b;
                b.x = fmaf(__expf(0.5f * l.x), e.x, m.x);
                b.y = fmaf(__expf(0.5f * l.y), e.y, m.y);
                b.z = fmaf(__expf(0.5f * l.z), e.z, m.z);
                b.w = fmaf(__expf(0.5f * l.w), e.w, m.w);
                bprev[j] = b;
            }
        }
    }

    // ---- main loop over timesteps in this chunk ----
    for (int t = t0; t < t0 + CHUNK; ++t) {
        const size_t po = ((size_t)k * TDIM + t) * VDIM;
        const size_t eo = ((size_t)t * KDIM + k) * VDIM;
        const float4* m4p = reinterpret_cast<const float4*>(mu_q + po);
        const float4* l4p = reinterpret_cast<const float4*>(lsq + po);
        const float4* e4p = reinterpret_cast<const float4*>(eps + eo);

        float lmax = -INFINITY;
#pragma unroll
        for (int j = 0; j < VPT; ++j) {
            const int idx = tid + j * BLOCK;
            if (idx < NV4) {
                const float4 m = m4p[idx];
                const float4 l = l4p[idx];
                const float4 e = e4p[idx];
                float4 b;
                b.x = fmaf(__expf(0.5f * l.x), e.x, m.x);
                b.y = fmaf(__expf(0.5f * l.y), e.y, m.y);
                b.z = fmaf(__expf(0.5f * l.z), e.z, m.z);
                b.w = fmaf(__expf(0.5f * l.w), e.w, m.w);

                if (t == 0) {
                    klacc += (__expf(l.x) + m.x * m.x) * inv1 - 1.0f - l.x;
                    klacc += (__expf(l.y) + m.y * m.y) * inv1 - 1.0f - l.y;
                    klacc += (__expf(l.z) + m.z * m.z) * inv1 - 1.0f - l.z;
                    klacc += (__expf(l.w) + m.w * m.w) * inv1 - 1.0f - l.w;
                } else {
                    const float4 p = bprev[j];
                    float dx = m.x - p.x, dy = m.y - p.y, dz = m.z - p.z, dw = m.w - p.w;
                    klacc += (__expf(l.x) + dx * dx) * invd - 1.0f + logd - l.x;
                    klacc += (__expf(l.y) + dy * dy) * invd - 1.0f + logd - l.y;
                    klacc += (__expf(l.z) + dz * dz) * invd - 1.0f + logd - l.z;
                    klacc += (__expf(l.w) + dw * dw) * invd - 1.0f + logd - l.w;
                }
                bprev[j] = b;
                lmax = fmaxf(lmax, fmaxf(fmaxf(b.x, b.y), fmaxf(b.z, b.w)));
            }
        }

        // ---- block-reduce max over the row ----
        float wm = wave_red_max(lmax);
        if ((tid & 63) == 0) red[tid >> 6] = wm;
        __syncthreads();
        float rowmax = red[0];
#pragma unroll
        for (int w = 1; w < NWAVE; ++w) rowmax = fmaxf(rowmax, red[w]);
        __syncthreads();

        // ---- sum of exp(beta - max) ----
        float lsum = 0.0f;
#pragma unroll
        for (int j = 0; j < VPT; ++j) {
            const int idx = tid + j * BLOCK;
            if (idx < NV4) {
                const float4 b = bprev[j];
                lsum += __expf(b.x - rowmax) + __expf(b.y - rowmax)
                      + __expf(b.z - rowmax) + __expf(b.w - rowmax);
            }
        }
        float ws = wave_red_sum(lsum);
        if ((tid & 63) == 0) red[tid >> 6] = ws;
        __syncthreads();
        float rowsum = 0.0f;
#pragma unroll
        for (int w = 0; w < NWAVE; ++w) rowsum += red[w];
        __syncthreads();
        const float invs = 1.0f / rowsum;

        // ---- write softmax ----
        float4* o4p = reinterpret_cast<float4*>(out + ((size_t)t * KDIM + k) * VDIM);
#pragma unroll
        for (int j = 0; j < VPT; ++j) {
            const int idx = tid + j * BLOCK;
            if (idx < NV4) {
                const float4 b = bprev[j];
                float4 o;
                o.x = __expf(b.x - rowmax) * invs;
                o.y = __expf(b.y - rowmax) * invs;
                o.z = __expf(b.z - rowmax) * invs;
                o.w = __expf(b.w - rowmax) * invs;
                o4p[idx] = o;
            }
        }
    }

    // ---- KL block reduction + one atomic per block ----
    float wk = wave_red_sum(klacc);
    if ((tid & 63) == 0) red[tid >> 6] = wk;
    __syncthreads();
    if (tid == 0) {
        float tot = 0.0f;
#pragma unroll
        for (int w = 0; w < NWAVE; ++w) tot += red[w];
        atomicAdd(kl, 0.5f * tot);
    }
}

extern "C" void kernel_launch(void* const* d_in, const int* in_sizes, int n_in,
                              void* d_out, int out_size, void* d_ws, size_t ws_size,
                              hipStream_t stream) {
    const float* mu_q = (const float*)d_in[0];  // [K,T,V]
    const float* lsq  = (const float*)d_in[1];  // [K,T,V]
    const float* eps  = (const float*)d_in[2];  // [T,K,V]
    float* out = (float*)d_out;                 // [T,K,V] softmax, then 1 float KL
    float* kl  = out + (size_t)TDIM * KDIM * VDIM;

    // zero the KL accumulator each launch (graph-capture-safe)
    hipMemsetAsync(kl, 0, sizeof(float), stream);

    dim3 grid(KDIM * NCHUNK);
    fused_beta_softmax_kl<<<grid, BLOCK, 0, stream>>>(mu_q, lsq, eps, out, kl);
}

// Round 3
// 263.658 us; speedup vs baseline: 1.6494x; 1.6494x over previous
//
#include <hip/hip_runtime.h>
#include <math.h>

#define KDIM 64
#define TDIM 100
#define VDIM 10000
#define NV4  2500            // VDIM / 4
#define BLOCK 256
#define NWAVE (BLOCK / 64)
#define VPT 10               // ceil(NV4 / BLOCK)
#define CHUNK 5
#define NCHUNK (TDIM / CHUNK)

__device__ __forceinline__ float wave_red_sum(float v) {
#pragma unroll
    for (int m = 32; m >= 1; m >>= 1) v += __shfl_xor(v, m, 64);
    return v;
}

__global__ __launch_bounds__(BLOCK) void fused_beta_softmax_kl(
    const float* __restrict__ mu_q,   // [K, T, V]
    const float* __restrict__ lsq,    // [K, T, V]
    const float* __restrict__ eps,    // [T, K, V]
    float* __restrict__ out,          // [T, K, V]
    float* __restrict__ kl)           // scalar (pre-zeroed)
{
    __shared__ float red[2][NWAVE];   // double-buffered per-t slots -> 1 barrier/t
    __shared__ float kred[NWAVE];

    const int tid = threadIdx.x;
    const int bid = blockIdx.x;
    const int k   = bid / NCHUNK;
    const int c   = bid % NCHUNK;
    const int t0  = c * CHUNK;

    const float inv1 = 1.0f / (1.0f + 1e-6f);
    const float invd = 1.0f / (0.005f + 1e-6f);
    const float logd = -5.2983173665480363f;   // log(0.005f) in fp32

    float4 bprev[VPT];
    float  klacc = 0.0f;

    // ---- chunk-boundary: recompute beta[t0-1] into registers ----
    if (t0 > 0) {
        const size_t po = ((size_t)k * TDIM + (t0 - 1)) * VDIM;
        const size_t eo = ((size_t)(t0 - 1) * KDIM + k) * VDIM;
        const float4* m4p = reinterpret_cast<const float4*>(mu_q + po);
        const float4* l4p = reinterpret_cast<const float4*>(lsq + po);
        const float4* e4p = reinterpret_cast<const float4*>(eps + eo);
#pragma unroll
        for (int j = 0; j < VPT; ++j) {
            const int idx = tid + j * BLOCK;
            if (idx < NV4) {
                const float4 m = m4p[idx];
                const float4 l = l4p[idx];
                const float4 e = e4p[idx];
                float4 b;
                b.x = fmaf(__expf(0.5f * l.x), e.x, m.x);
                b.y = fmaf(__expf(0.5f * l.y), e.y, m.y);
                b.z = fmaf(__expf(0.5f * l.z), e.z, m.z);
                b.w = fmaf(__expf(0.5f * l.w), e.w, m.w);
                bprev[j] = b;
            }
        }
    }

    // ---- main loop over timesteps in this chunk ----
    for (int t = t0; t < t0 + CHUNK; ++t) {
        const size_t po = ((size_t)k * TDIM + t) * VDIM;
        const size_t eo = ((size_t)t * KDIM + k) * VDIM;
        const float4* m4p = reinterpret_cast<const float4*>(mu_q + po);
        const float4* l4p = reinterpret_cast<const float4*>(lsq + po);
        const float4* e4p = reinterpret_cast<const float4*>(eps + eo);

        // ---- fused: load, beta, KL, online sum-of-exp (no max pass) ----
        float lsum = 0.0f;
#pragma unroll
        for (int j = 0; j < VPT; ++j) {
            const int idx = tid + j * BLOCK;
            if (idx < NV4) {
                const float4 m = m4p[idx];
                const float4 l = l4p[idx];
                const float4 e = e4p[idx];
                float4 b;
                b.x = fmaf(__expf(0.5f * l.x), e.x, m.x);
                b.y = fmaf(__expf(0.5f * l.y), e.y, m.y);
                b.z = fmaf(__expf(0.5f * l.z), e.z, m.z);
                b.w = fmaf(__expf(0.5f * l.w), e.w, m.w);

                if (t == 0) {
                    klacc += (__expf(l.x) + m.x * m.x) * inv1 - 1.0f - l.x;
                    klacc += (__expf(l.y) + m.y * m.y) * inv1 - 1.0f - l.y;
                    klacc += (__expf(l.z) + m.z * m.z) * inv1 - 1.0f - l.z;
                    klacc += (__expf(l.w) + m.w * m.w) * inv1 - 1.0f - l.w;
                } else {
                    const float4 p = bprev[j];
                    float dx = m.x - p.x, dy = m.y - p.y, dz = m.z - p.z, dw = m.w - p.w;
                    klacc += (__expf(l.x) + dx * dx) * invd - 1.0f + logd - l.x;
                    klacc += (__expf(l.y) + dy * dy) * invd - 1.0f + logd - l.y;
                    klacc += (__expf(l.z) + dz * dz) * invd - 1.0f + logd - l.z;
                    klacc += (__expf(l.w) + dw * dw) * invd - 1.0f + logd - l.w;
                }
                bprev[j] = b;
                lsum += __expf(b.x) + __expf(b.y) + __expf(b.z) + __expf(b.w);
            }
        }

        // ---- single-barrier block reduce of the exp-sum ----
        const int slot = t & 1;
        float ws = wave_red_sum(lsum);
        if ((tid & 63) == 0) red[slot][tid >> 6] = ws;
        __syncthreads();
        float rowsum = 0.0f;
#pragma unroll
        for (int w = 0; w < NWAVE; ++w) rowsum += red[slot][w];
        const float invs = 1.0f / rowsum;

        // ---- write softmax = exp(beta) * invs ----
        float4* o4p = reinterpret_cast<float4*>(out + ((size_t)t * KDIM + k) * VDIM);
#pragma unroll
        for (int j = 0; j < VPT; ++j) {
            const int idx = tid + j * BLOCK;
            if (idx < NV4) {
                const float4 b = bprev[j];
                float4 o;
                o.x = __expf(b.x) * invs;
                o.y = __expf(b.y) * invs;
                o.z = __expf(b.z) * invs;
                o.w = __expf(b.w) * invs;
                o4p[idx] = o;
            }
        }
        // no trailing barrier: next t writes red[!slot], reads complete before
        // its own __syncthreads; red[slot] isn't touched until t+2's barrier.
    }

    // ---- KL block reduction + one atomic per block ----
    float wk = wave_red_sum(klacc);
    __syncthreads();                      // ensure last rowsum reads are done
    if ((tid & 63) == 0) kred[tid >> 6] = wk;
    __syncthreads();
    if (tid == 0) {
        float tot = 0.0f;
#pragma unroll
        for (int w = 0; w < NWAVE; ++w) tot += kred[w];
        atomicAdd(kl, 0.5f * tot);
    }
}

extern "C" void kernel_launch(void* const* d_in, const int* in_sizes, int n_in,
                              void* d_out, int out_size, void* d_ws, size_t ws_size,
                              hipStream_t stream) {
    const float* mu_q = (const float*)d_in[0];  // [K,T,V]
    const float* lsq  = (const float*)d_in[1];  // [K,T,V]
    const float* eps  = (const float*)d_in[2];  // [T,K,V]
    float* out = (float*)d_out;                 // [T,K,V] softmax, then 1 float KL
    float* kl  = out + (size_t)TDIM * KDIM * VDIM;

    // zero the KL accumulator each launch (graph-capture-safe)
    hipMemsetAsync(kl, 0, sizeof(float), stream);

    dim3 grid(KDIM * NCHUNK);
    fused_beta_softmax_kl<<<grid, BLOCK, 0, stream>>>(mu_q, lsq, eps, out, kl);
}

// Round 4
// 238.892 us; speedup vs baseline: 1.8204x; 1.1037x over previous
//
#include <hip/hip_runtime.h>
#include <math.h>

#define KDIM 64
#define TDIM 100
#define VDIM 10000
#define NV4  2500            // VDIM / 4
#define BLOCK 256
#define NWAVE (BLOCK / 64)
#define VPT 10               // ceil(NV4 / BLOCK)
#define HALF 5
#define CHUNK 5
#define NCHUNK (TDIM / CHUNK)

#define INV1 (1.0f / (1.0f + 1e-6f))
#define INVD (1.0f / (0.005f + 1e-6f))
#define LOGD (-5.2983173665480363f)   // log(0.005f)

__device__ __forceinline__ float wave_red_sum(float v) {
#pragma unroll
    for (int m = 32; m >= 1; m >>= 1) v += __shfl_xor(v, m, 64);
    return v;
}

// beta + KL + exp-sum for one float4, updating bprev slot in place
__device__ __forceinline__ void consume(const float4 m, const float4 l, const float4 e,
                                        float4& bp, const bool first,
                                        float& klacc, float& lsum) {
    float4 b;
    b.x = fmaf(__expf(0.5f * l.x), e.x, m.x);
    b.y = fmaf(__expf(0.5f * l.y), e.y, m.y);
    b.z = fmaf(__expf(0.5f * l.z), e.z, m.z);
    b.w = fmaf(__expf(0.5f * l.w), e.w, m.w);
    if (first) {
        klacc += (__expf(l.x) + m.x * m.x) * INV1 - 1.0f - l.x;
        klacc += (__expf(l.y) + m.y * m.y) * INV1 - 1.0f - l.y;
        klacc += (__expf(l.z) + m.z * m.z) * INV1 - 1.0f - l.z;
        klacc += (__expf(l.w) + m.w * m.w) * INV1 - 1.0f - l.w;
    } else {
        const float dx = m.x - bp.x, dy = m.y - bp.y, dz = m.z - bp.z, dw = m.w - bp.w;
        klacc += (__expf(l.x) + dx * dx) * INVD - 1.0f + LOGD - l.x;
        klacc += (__expf(l.y) + dy * dy) * INVD - 1.0f + LOGD - l.y;
        klacc += (__expf(l.z) + dz * dz) * INVD - 1.0f + LOGD - l.z;
        klacc += (__expf(l.w) + dw * dw) * INVD - 1.0f + LOGD - l.w;
    }
    bp = b;
    lsum += __expf(b.x) + __expf(b.y) + __expf(b.z) + __expf(b.w);
}

__global__ __launch_bounds__(BLOCK) void fused_beta_softmax_kl(
    const float* __restrict__ mu_q,   // [K, T, V]
    const float* __restrict__ lsq,    // [K, T, V]
    const float* __restrict__ eps,    // [T, K, V]
    float* __restrict__ out,          // [T, K, V]
    float* __restrict__ kl)           // scalar (pre-zeroed)
{
    __shared__ float red[2][NWAVE];
    __shared__ float kred[NWAVE];

    const int tid = threadIdx.x;
    const int bid = blockIdx.x;
    const int k   = bid / NCHUNK;
    const int c   = bid % NCHUNK;
    const int t0  = c * CHUNK;

    float4 bprev[VPT];
    float  klacc = 0.0f;

    float4 M[HALF], L[HALF], E[HALF];

    // ---- chunk-boundary: recompute beta[t0-1] (batched loads) ----
    if (t0 > 0) {
        const size_t po = ((size_t)k * TDIM + (t0 - 1)) * VDIM;
        const size_t eo = ((size_t)(t0 - 1) * KDIM + k) * VDIM;
        const float4* m4p = reinterpret_cast<const float4*>(mu_q + po);
        const float4* l4p = reinterpret_cast<const float4*>(lsq + po);
        const float4* e4p = reinterpret_cast<const float4*>(eps + eo);
        // half 0: idx <= 255 + 4*256 = 1279 < 2500, no guard
#pragma unroll
        for (int jj = 0; jj < HALF; ++jj) {
            const int idx = tid + jj * BLOCK;
            M[jj] = m4p[idx]; L[jj] = l4p[idx]; E[jj] = e4p[idx];
        }
#pragma unroll
        for (int jj = 0; jj < HALF; ++jj) {
            float4 b;
            b.x = fmaf(__expf(0.5f * L[jj].x), E[jj].x, M[jj].x);
            b.y = fmaf(__expf(0.5f * L[jj].y), E[jj].y, M[jj].y);
            b.z = fmaf(__expf(0.5f * L[jj].z), E[jj].z, M[jj].z);
            b.w = fmaf(__expf(0.5f * L[jj].w), E[jj].w, M[jj].w);
            bprev[jj] = b;
        }
        // half 1: guard
#pragma unroll
        for (int jj = 0; jj < HALF; ++jj) {
            const int idx = tid + (HALF + jj) * BLOCK;
            if (idx < NV4) { M[jj] = m4p[idx]; L[jj] = l4p[idx]; E[jj] = e4p[idx]; }
        }
#pragma unroll
        for (int jj = 0; jj < HALF; ++jj) {
            const int idx = tid + (HALF + jj) * BLOCK;
            if (idx < NV4) {
                float4 b;
                b.x = fmaf(__expf(0.5f * L[jj].x), E[jj].x, M[jj].x);
                b.y = fmaf(__expf(0.5f * L[jj].y), E[jj].y, M[jj].y);
                b.z = fmaf(__expf(0.5f * L[jj].z), E[jj].z, M[jj].z);
                b.w = fmaf(__expf(0.5f * L[jj].w), E[jj].w, M[jj].w);
                bprev[HALF + jj] = b;
            }
        }
    }

    // ---- main loop over timesteps in this chunk ----
    for (int t = t0; t < t0 + CHUNK; ++t) {
        const size_t po = ((size_t)k * TDIM + t) * VDIM;
        const size_t eo = ((size_t)t * KDIM + k) * VDIM;
        const float4* m4p = reinterpret_cast<const float4*>(mu_q + po);
        const float4* l4p = reinterpret_cast<const float4*>(lsq + po);
        const float4* e4p = reinterpret_cast<const float4*>(eps + eo);
        const bool first = (t == 0);

        float lsum = 0.0f;

        // ---- half 0: 15 loads in flight, then consume (no guard) ----
#pragma unroll
        for (int jj = 0; jj < HALF; ++jj) {
            const int idx = tid + jj * BLOCK;
            M[jj] = m4p[idx]; L[jj] = l4p[idx]; E[jj] = e4p[idx];
        }
#pragma unroll
        for (int jj = 0; jj < HALF; ++jj)
            consume(M[jj], L[jj], E[jj], bprev[jj], first, klacc, lsum);

        // ---- half 1: guarded ----
#pragma unroll
        for (int jj = 0; jj < HALF; ++jj) {
            const int idx = tid + (HALF + jj) * BLOCK;
            if (idx < NV4) { M[jj] = m4p[idx]; L[jj] = l4p[idx]; E[jj] = e4p[idx]; }
        }
#pragma unroll
        for (int jj = 0; jj < HALF; ++jj) {
            const int idx = tid + (HALF + jj) * BLOCK;
            if (idx < NV4)
                consume(M[jj], L[jj], E[jj], bprev[HALF + jj], first, klacc, lsum);
        }

        // ---- single-barrier block reduce of the exp-sum ----
        const int slot = t & 1;
        float ws = wave_red_sum(lsum);
        if ((tid & 63) == 0) red[slot][tid >> 6] = ws;
        __syncthreads();
        float rowsum = 0.0f;
#pragma unroll
        for (int w = 0; w < NWAVE; ++w) rowsum += red[slot][w];
        const float invs = 1.0f / rowsum;

        // ---- write softmax = exp(beta) * invs ----
        float4* o4p = reinterpret_cast<float4*>(out + ((size_t)t * KDIM + k) * VDIM);
#pragma unroll
        for (int j = 0; j < VPT; ++j) {
            const int idx = tid + j * BLOCK;
            if (idx < NV4) {
                const float4 b = bprev[j];
                float4 o;
                o.x = __expf(b.x) * invs;
                o.y = __expf(b.y) * invs;
                o.z = __expf(b.z) * invs;
                o.w = __expf(b.w) * invs;
                o4p[idx] = o;
            }
        }
    }

    // ---- KL block reduction + one atomic per block ----
    float wk = wave_red_sum(klacc);
    __syncthreads();
    if ((tid & 63) == 0) kred[tid >> 6] = wk;
    __syncthreads();
    if (tid == 0) {
        float tot = 0.0f;
#pragma unroll
        for (int w = 0; w < NWAVE; ++w) tot += kred[w];
        atomicAdd(kl, 0.5f * tot);
    }
}

extern "C" void kernel_launch(void* const* d_in, const int* in_sizes, int n_in,
                              void* d_out, int out_size, void* d_ws, size_t ws_size,
                              hipStream_t stream) {
    const float* mu_q = (const float*)d_in[0];  // [K,T,V]
    const float* lsq  = (const float*)d_in[1];  // [K,T,V]
    const float* eps  = (const float*)d_in[2];  // [T,K,V]
    float* out = (float*)d_out;                 // [T,K,V] softmax, then 1 float KL
    float* kl  = out + (size_t)TDIM * KDIM * VDIM;

    // zero the KL accumulator each launch (graph-capture-safe)
    hipMemsetAsync(kl, 0, sizeof(float), stream);

    dim3 grid(KDIM * NCHUNK);
    fused_beta_softmax_kl<<<grid, BLOCK, 0, stream>>>(mu_q, lsq, eps, out, kl);
}